// Round 4
// baseline (516.977 us; speedup 1.0000x reference)
//
#include <hip/hip_runtime.h>

typedef unsigned int u32;

#define BB 64
#define HH 512
#define WW 512
#define HWP 262144            // 512*512
#define WPI 8192              // words per image (512*16)
#define NBV 1024              // value histogram bins
#define NBS 512               // score histogram bins
#define EPSF 1e-8f
#define NBGK 78643            // int(0.3 * 512*512)
#define CAND_CAP 4096
#define SEL_CAP 128
#define PN 20

// prm fields per image:
// 0 nfg, 1 deg, 2 Bf, 3 rf, 4 Bb, 5 rb, 6 ubf, 7 ibf, 8 ubb, 9 ibb,
// 10 sbf, 12 needf, 13 sbb, 15 needb

__device__ __forceinline__ int vbucket(float vb){
    int b = (int)(vb * (float)NBV);
    b = b < 0 ? 0 : b;
    return b > (NBV-1) ? (NBV-1) : b;
}
__device__ __forceinline__ int sbucket(float s){
    float a = (s + 24.0f) * ((float)NBS / 44.0f);
    a = fmaxf(a, 0.0f);
    int b = (int)a;
    return b > (NBS-1) ? (NBS-1) : b;
}
__device__ __forceinline__ u32 flipf(float s){
    u32 u = __float_as_uint(s);
    u32 m = (u & 0x80000000u) ? 0xFFFFFFFFu : 0x80000000u;
    return u ^ m;
}

// XCD-local remap: all 32 blocks of an image share (bid & 7) residue.
__device__ __forceinline__ void imgblk(int bid, int& img, int& blk){
    int r = bid & 7, s = bid >> 3;
    img = ((s >> 5) << 3) | r;
    blk = s & 31;
}

// K1: roi bits (LDS) -> h-erode -> roiH; bg value hist (1024 bins); min/max.
// Block owns 16 complete rows, so 11-wide h-erosion is block-local.
__global__ __launch_bounds__(256) void k_prep(const float* __restrict__ x,
        const float* __restrict__ thr, u32* __restrict__ roiH,
        u32* __restrict__ ghist_bg, u32* __restrict__ minb, u32* __restrict__ maxb)
{
    __shared__ u32 hist[NBV];
    __shared__ u32 A[256];
    int t = threadIdx.x;
    for (int i = t; i < NBV; i += 256) hist[i] = 0u;
    A[t] = 0u;
    __syncthreads();
    int img, blk;
    imgblk(blockIdx.x, img, blk);
    const float4* c4 = (const float4*)x + (size_t)img * (HWP/4) + (size_t)blk * 2048;
    float th = thr[img];
    th = (th == 0.0f) ? 1.0f : ((th == 255.0f) ? 254.0f : th);
    u32 mn = 0xFFFFFFFFu, mx = 0u;
    #pragma unroll
    for (int k = 0; k < 8; k++){
        float4 v4 = c4[k*256 + t];
        float vv[4] = {v4.x, v4.y, v4.z, v4.w};
        u32 nib = 0u;
        #pragma unroll
        for (int c = 0; c < 4; c++){
            float v = vv[c];
            u32 ub = __float_as_uint(v);
            mn = mn < ub ? mn : ub;
            mx = mx > ub ? mx : ub;
            if (floorf(v * 255.0f) > th) nib |= (1u << c);
            atomicAdd(&hist[vbucket(v + EPSF)], 1u);
        }
        if (nib) atomicOr(&A[k*32 + (t>>3)], nib << ((t&7)*4));
    }
    for (int o = 32; o >= 1; o >>= 1){
        u32 m2 = __shfl_down(mn, o); mn = mn < m2 ? mn : m2;
        u32 m3 = __shfl_down(mx, o); mx = mx > m3 ? mx : m3;
    }
    if ((t & 63) == 0){ atomicMin(&minb[img], mn); atomicMax(&maxb[img], mx); }
    __syncthreads();
    // h-erode word t (16 rows x 16 words, row-local)
    {
        int wr = t & 15;
        u32 cur = A[t];
        u32 left  = (wr > 0)  ? A[t-1] : 0xFFFFFFFFu;
        u32 right = (wr < 15) ? A[t+1] : 0xFFFFFFFFu;
        u32 res = cur;
        #pragma unroll
        for (int d = 1; d <= 5; d++){
            res &= (cur >> d) | (right << (32 - d));
            res &= (cur << d) | (left  >> (32 - d));
        }
        roiH[(size_t)img*WPI + blk*256 + t] = res;
    }
    for (int i = t; i < NBV; i += 256){
        u32 h = hist[i];
        if (h) atomicAdd(&ghist_bg[(size_t)img*NBV + i], h);
    }
}

// K2: v-erode roiH -> roiE + roiSum, fused fg value histogram.
__global__ __launch_bounds__(256) void k_vfg(const float* __restrict__ x,
        const u32* __restrict__ roiH, u32* __restrict__ roiE,
        u32* __restrict__ roiSum, u32* __restrict__ ghist_fg)
{
    __shared__ u32 hist[NBV];
    __shared__ u32 W[256];
    int t = threadIdx.x;
    for (int i = t; i < NBV; i += 256) hist[i] = 0u;
    int img, blk;
    imgblk(blockIdx.x, img, blk);
    const u32* rp = roiH + (size_t)img * WPI;
    int iw = blk*256 + t;
    int r = iw >> 4;
    u32 res = 0xFFFFFFFFu;
    #pragma unroll
    for (int d = -5; d <= 5; d++){
        int rr = r + d;
        if (rr >= 0 && rr < HH) res &= rp[iw + d*16];
    }
    W[t] = res;
    roiE[(size_t)img*WPI + iw] = res;
    u32 cnt = __popc(res);
    for (int o = 32; o >= 1; o >>= 1) cnt += __shfl_down(cnt, o);
    if ((t & 63) == 0) atomicAdd(&roiSum[img], cnt);
    __syncthreads();
    const float4* c4 = (const float4*)x + (size_t)img * (HWP/4) + (size_t)blk * 2048;
    #pragma unroll
    for (int k = 0; k < 8; k++){
        u32 nib = (W[k*32 + (t>>3)] >> ((t&7)*4)) & 0xFu;
        if (nib){
            float4 v4 = c4[k*256 + t];
            float vv[4] = {v4.x, v4.y, v4.z, v4.w};
            #pragma unroll
            for (int c = 0; c < 4; c++){
                if ((nib >> c) & 1u) atomicAdd(&hist[vbucket(vv[c] + EPSF)], 1u);
            }
        }
    }
    __syncthreads();
    for (int i = t; i < NBV; i += 256){
        u32 h = hist[i];
        if (h) atomicAdd(&ghist_fg[(size_t)img*NBV + i], h);
    }
}

// K3: per-image scan of value hists -> boundary bucket + in-bucket rank
__global__ __launch_bounds__(256) void k_bound1(const u32* __restrict__ ghf, const u32* __restrict__ ghb,
        const u32* __restrict__ minb, const u32* __restrict__ maxb, const u32* __restrict__ roiSum,
        int* __restrict__ prm)
{
    int b = blockIdx.x, t = threadIdx.x;
    __shared__ int partial[256];
    __shared__ int res[2];
    int deg = (minb[b] == maxb[b]) ? 1 : 0;
    int nfg = (int)floorf(0.3f * (float)(int)roiSum[b]);
    int Bf = -1, rf = 0, Bb = -1, rb = 0;
    if (!deg && nfg > 0){
        const u32* hh = ghf + (size_t)b * NBV;
        int s = 0;
        for (int i = 0; i < 4; i++) s += (int)hh[NBV-1 - (t*4+i)];
        partial[t] = s;
        __syncthreads();
        if (t == 0){
            int cum = 0, q = 0;
            for (; q < 256; q++){ if (cum + partial[q] >= nfg) break; cum += partial[q]; }
            for (int i = 0; i < 4; i++){
                int bkt = NBV-1 - (q*4+i);
                int h = (int)hh[bkt];
                if (cum + h >= nfg){ res[0] = bkt; res[1] = nfg - cum; break; }
                cum += h;
            }
        }
        __syncthreads();
        Bf = res[0]; rf = res[1];
        __syncthreads();
    }
    if (!deg){
        const u32* hh = ghb + (size_t)b * NBV;
        int s = 0;
        for (int i = 0; i < 4; i++) s += (int)hh[t*4+i];
        partial[t] = s;
        __syncthreads();
        if (t == 0){
            int cum = 0, q = 0;
            for (; q < 256; q++){ if (cum + partial[q] >= NBGK) break; cum += partial[q]; }
            for (int i = 0; i < 4; i++){
                int bkt = q*4+i;
                int h = (int)hh[bkt];
                if (cum + h >= NBGK){ res[0] = bkt; res[1] = NBGK - cum; break; }
                cum += h;
            }
        }
        __syncthreads();
        Bb = res[0]; rb = res[1];
    }
    if (t == 0){
        int* p = prm + b * PN;
        p[0] = nfg; p[1] = deg; p[2] = Bf; p[3] = rf; p[4] = Bb; p[5] = rb;
    }
}

// K4: collect boundary-bucket candidates
__global__ __launch_bounds__(256) void k_collect1(const float* __restrict__ x, const u32* __restrict__ roiE,
        const int* __restrict__ prm,
        uint2* __restrict__ candF, u32* __restrict__ cntF,
        uint2* __restrict__ candB, u32* __restrict__ cntB)
{
    __shared__ u32 words[256];
    int img, blk;
    imgblk(blockIdx.x, img, blk);
    int t = threadIdx.x;
    int Bf = prm[img*PN + 2];
    int Bb = prm[img*PN + 4];
    words[t] = roiE[(size_t)img*WPI + blk*256 + t];
    __syncthreads();
    const float4* c4 = (const float4*)x + (size_t)img * (HWP/4) + (size_t)blk * 2048;
    #pragma unroll
    for (int k = 0; k < 8; k++){
        float4 v4 = c4[k*256 + t];
        float vv[4] = {v4.x, v4.y, v4.z, v4.w};
        u32 nib = (words[k*32 + (t>>3)] >> ((t&7)*4)) & 0xFu;
        int pix0 = blk*8192 + k*1024 + t*4;
        #pragma unroll
        for (int c = 0; c < 4; c++){
            float vb = vv[c] + EPSF;
            int bkt = vbucket(vb);
            int pix = pix0 + c;
            if (bkt == Bb){
                u32 q = atomicAdd(&cntB[img], 1u);
                if (q < CAND_CAP) candB[(size_t)img*CAND_CAP + q] = make_uint2(__float_as_uint(vb), (u32)pix);
            }
            if (bkt == Bf && ((nib >> c) & 1u)){
                u32 q = atomicAdd(&cntF[img], 1u);
                if (q < CAND_CAP) candF[(size_t)img*CAND_CAP + q] = make_uint2(__float_as_uint(vb), (u32)pix);
            }
        }
    }
}

// K5: resolve exact (bits, idx) threshold within boundary bucket
__global__ __launch_bounds__(256) void k_resolve1(const uint2* __restrict__ candF, const u32* __restrict__ cntF,
        const uint2* __restrict__ candB, const u32* __restrict__ cntB, int* __restrict__ prm)
{
    int b = blockIdx.x, t = threadIdx.x;
    __shared__ uint2 c[CAND_CAP];
    int rf = prm[b*PN + 3];
    if (rf > 0){
        int m = (int)cntF[b]; m = m < CAND_CAP ? m : CAND_CAP;
        for (int i = t; i < m; i += 256) c[i] = candF[(size_t)b*CAND_CAP + i];
        __syncthreads();
        for (int i = t; i < m; i += 256){
            u32 ki = c[i].x, xi = c[i].y;
            int r = 0;
            for (int j = 0; j < m; j++){
                u32 kj = c[j].x, xj = c[j].y;
                r += (kj > ki) || (kj == ki && xj < xi);
            }
            if (r == rf - 1){ prm[b*PN + 6] = (int)ki; prm[b*PN + 7] = (int)xi; }
        }
    } else if (t == 0){
        prm[b*PN + 6] = (int)0xFFFFFFFFu; prm[b*PN + 7] = -1;
    }
    __syncthreads();
    int rb = prm[b*PN + 5];
    if (rb > 0){
        int m = (int)cntB[b]; m = m < CAND_CAP ? m : CAND_CAP;
        for (int i = t; i < m; i += 256) c[i] = candB[(size_t)b*CAND_CAP + i];
        __syncthreads();
        for (int i = t; i < m; i += 256){
            u32 ki = c[i].x, xi = c[i].y;
            int r = 0;
            for (int j = 0; j < m; j++){
                u32 kj = c[j].x, xj = c[j].y;
                r += (kj < ki) || (kj == ki && xj < xi);
            }
            if (r == rb - 1){ prm[b*PN + 8] = (int)ki; prm[b*PN + 9] = (int)xi; }
        }
    } else if (t == 0){
        prm[b*PN + 8] = 0; prm[b*PN + 9] = -1;
    }
}

// K6: score histograms for masked fg/bg pixels
__global__ __launch_bounds__(256) void k_shist(const float* __restrict__ x, const u32* __restrict__ roiE,
        const float* __restrict__ ufg, const float* __restrict__ ubg, const int* __restrict__ prm,
        u32* __restrict__ shfG, u32* __restrict__ shbG)
{
    __shared__ u32 hf[NBS];
    __shared__ u32 hb[NBS];
    __shared__ u32 words[256];
    int t = threadIdx.x;
    for (int i = t; i < NBS; i += 256){ hf[i] = 0u; hb[i] = 0u; }
    int img, blk;
    imgblk(blockIdx.x, img, blk);
    words[t] = roiE[(size_t)img*WPI + blk*256 + t];
    __syncthreads();
    const int* p = prm + img*PN;
    u32 ubf = (u32)p[6]; int ibf = p[7];
    u32 ubb = (u32)p[8]; int ibb = p[9];
    size_t b4 = (size_t)img * (HWP/4) + (size_t)blk * 2048;
    const float4* c4 = (const float4*)x + b4;
    const float4* uf4 = (const float4*)ufg + b4;
    const float4* ub4 = (const float4*)ubg + b4;
    #pragma unroll
    for (int k = 0; k < 8; k++){
        float4 v4 = c4[k*256 + t];
        float vv[4] = {v4.x, v4.y, v4.z, v4.w};
        u32 nib = (words[k*32 + (t>>3)] >> ((t&7)*4)) & 0xFu;
        int pix0 = blk*8192 + k*1024 + t*4;
        float vbv[4]; bool fm[4], bm[4]; bool anyf = false, anyb = false;
        #pragma unroll
        for (int c = 0; c < 4; c++){
            float vb = vv[c] + EPSF;
            vbv[c] = vb;
            u32 bu = __float_as_uint(vb);
            int pix = pix0 + c;
            fm[c] = ((nib >> c) & 1u) && (bu > ubf || (bu == ubf && pix <= ibf));
            bm[c] = (bu < ubb || (bu == ubb && pix <= ibb));
            anyf |= fm[c]; anyb |= bm[c];
        }
        if (anyf){
            float4 u4 = uf4[k*256 + t];
            float uu[4] = {u4.x, u4.y, u4.z, u4.w};
            #pragma unroll
            for (int c = 0; c < 4; c++){
                if (fm[c]){
                    float s = logf(vbv[c]) - logf(-logf(uu[c]));
                    atomicAdd(&hf[sbucket(s)], 1u);
                }
            }
        }
        if (anyb){
            float4 u4 = ub4[k*256 + t];
            float uu[4] = {u4.x, u4.y, u4.z, u4.w};
            #pragma unroll
            for (int c = 0; c < 4; c++){
                if (bm[c]){
                    float pb = fmaxf(1.0f - vbv[c], 0.0f) + EPSF;
                    float s = logf(pb) - logf(-logf(uu[c]));
                    atomicAdd(&hb[sbucket(s)], 1u);
                }
            }
        }
    }
    __syncthreads();
    for (int i = t; i < NBS; i += 256){
        u32 h = hf[i]; if (h) atomicAdd(&shfG[(size_t)img*NBS + i], h);
        h = hb[i];     if (h) atomicAdd(&shbG[(size_t)img*NBS + i], h);
    }
}

// K7: scan score hists -> boundary bucket + needed-from-boundary counts
__global__ __launch_bounds__(256) void k_bound2(const u32* __restrict__ shfG, const u32* __restrict__ shbG,
        int* __restrict__ prm)
{
    int b = blockIdx.x, t = threadIdx.x;
    __shared__ int partial[256];
    __shared__ int res[2];
    int* p = prm + b*PN;
    int nfg = p[0], deg = p[1];
    int kf = (deg || nfg <= 0) ? 0 : (nfg < 100 ? nfg : 100);
    int kb = deg ? 0 : 100;
    int sbf = 0x7FFFFFFF, needf = 0, sbb = 0x7FFFFFFF, needb = 0;
    if (kf > 0){
        const u32* hh = shfG + (size_t)b * NBS;
        int s = 0;
        for (int i = 0; i < 2; i++) s += (int)hh[NBS-1 - (t*2+i)];
        partial[t] = s;
        __syncthreads();
        if (t == 0){
            int cum = 0, q = 0;
            for (; q < 256; q++){ if (cum + partial[q] >= kf) break; cum += partial[q]; }
            for (int i = 0; i < 2; i++){
                int bkt = NBS-1 - (q*2+i);
                int h = (int)hh[bkt];
                if (cum + h >= kf){ res[0] = bkt; res[1] = kf - cum; break; }
                cum += h;
            }
        }
        __syncthreads();
        sbf = res[0]; needf = res[1];
        __syncthreads();
    }
    if (kb > 0){
        const u32* hh = shbG + (size_t)b * NBS;
        int s = 0;
        for (int i = 0; i < 2; i++) s += (int)hh[NBS-1 - (t*2+i)];
        partial[t] = s;
        __syncthreads();
        if (t == 0){
            int cum = 0, q = 0;
            for (; q < 256; q++){ if (cum + partial[q] >= kb) break; cum += partial[q]; }
            for (int i = 0; i < 2; i++){
                int bkt = NBS-1 - (q*2+i);
                int h = (int)hh[bkt];
                if (cum + h >= kb){ res[0] = bkt; res[1] = kb - cum; break; }
                cum += h;
            }
        }
        __syncthreads();
        sbb = res[0]; needb = res[1];
    }
    if (t == 0){
        p[10] = sbf; p[12] = needf; p[13] = sbb; p[15] = needb;
    }
}

// K8: collect score winners + boundary candidates
__global__ __launch_bounds__(256) void k_collect2(const float* __restrict__ x, const u32* __restrict__ roiE,
        const float* __restrict__ ufg, const float* __restrict__ ubg, const int* __restrict__ prm,
        uint2* __restrict__ selF, u32* __restrict__ cntSelF, uint2* __restrict__ scandF, u32* __restrict__ cntScF,
        uint2* __restrict__ selB, u32* __restrict__ cntSelB, uint2* __restrict__ scandB, u32* __restrict__ cntScB)
{
    __shared__ u32 words[256];
    int img, blk;
    imgblk(blockIdx.x, img, blk);
    int t = threadIdx.x;
    words[t] = roiE[(size_t)img*WPI + blk*256 + t];
    __syncthreads();
    const int* p = prm + img*PN;
    u32 ubf = (u32)p[6]; int ibf = p[7];
    u32 ubb = (u32)p[8]; int ibb = p[9];
    int sbf = p[10], sbb = p[13];
    size_t b4 = (size_t)img * (HWP/4) + (size_t)blk * 2048;
    const float4* c4 = (const float4*)x + b4;
    const float4* uf4 = (const float4*)ufg + b4;
    const float4* ub4 = (const float4*)ubg + b4;
    #pragma unroll
    for (int k = 0; k < 8; k++){
        float4 v4 = c4[k*256 + t];
        float vv[4] = {v4.x, v4.y, v4.z, v4.w};
        u32 nib = (words[k*32 + (t>>3)] >> ((t&7)*4)) & 0xFu;
        int pix0 = blk*8192 + k*1024 + t*4;
        float vbv[4]; bool fm[4], bm[4]; bool anyf = false, anyb = false;
        #pragma unroll
        for (int c = 0; c < 4; c++){
            float vb = vv[c] + EPSF;
            vbv[c] = vb;
            u32 bu = __float_as_uint(vb);
            int pix = pix0 + c;
            fm[c] = ((nib >> c) & 1u) && (bu > ubf || (bu == ubf && pix <= ibf));
            bm[c] = (bu < ubb || (bu == ubb && pix <= ibb));
            anyf |= fm[c]; anyb |= bm[c];
        }
        if (anyf){
            float4 u4 = uf4[k*256 + t];
            float uu[4] = {u4.x, u4.y, u4.z, u4.w};
            #pragma unroll
            for (int c = 0; c < 4; c++){
                if (fm[c]){
                    float s = logf(vbv[c]) - logf(-logf(uu[c]));
                    int sb = sbucket(s);
                    if (sb > sbf){
                        u32 q = atomicAdd(&cntSelF[img], 1u);
                        if (q < SEL_CAP) selF[(size_t)img*SEL_CAP + q] = make_uint2(flipf(s), (u32)(pix0 + c));
                    } else if (sb == sbf){
                        u32 q = atomicAdd(&cntScF[img], 1u);
                        if (q < CAND_CAP) scandF[(size_t)img*CAND_CAP + q] = make_uint2(flipf(s), (u32)(pix0 + c));
                    }
                }
            }
        }
        if (anyb){
            float4 u4 = ub4[k*256 + t];
            float uu[4] = {u4.x, u4.y, u4.z, u4.w};
            #pragma unroll
            for (int c = 0; c < 4; c++){
                if (bm[c]){
                    float pb = fmaxf(1.0f - vbv[c], 0.0f) + EPSF;
                    float s = logf(pb) - logf(-logf(uu[c]));
                    int sb = sbucket(s);
                    if (sb > sbb){
                        u32 q = atomicAdd(&cntSelB[img], 1u);
                        if (q < SEL_CAP) selB[(size_t)img*SEL_CAP + q] = make_uint2(flipf(s), (u32)(pix0 + c));
                    } else if (sb == sbb){
                        u32 q = atomicAdd(&cntScB[img], 1u);
                        if (q < CAND_CAP) scandB[(size_t)img*CAND_CAP + q] = make_uint2(flipf(s), (u32)(pix0 + c));
                    }
                }
            }
        }
    }
}

// K9: finalize top-k seed sets -> global seed lists
__global__ __launch_bounds__(256) void k_seeds(
        const uint2* __restrict__ selF, const u32* __restrict__ cntSelF,
        const uint2* __restrict__ scandF, const u32* __restrict__ cntScF,
        const uint2* __restrict__ selB, const u32* __restrict__ cntSelB,
        const uint2* __restrict__ scandB, const u32* __restrict__ cntScB,
        const int* __restrict__ prm,
        int* __restrict__ gSeedF, int* __restrict__ gnF,
        int* __restrict__ gSeedB, int* __restrict__ gnB)
{
    int b = blockIdx.x, t = threadIdx.x;
    __shared__ uint2 c[CAND_CAP];
    __shared__ int seedF[SEL_CAP];
    __shared__ int seedB[SEL_CAP];
    __shared__ int nF, nB;
    const int* p = prm + b*PN;
    int needf = p[12], needb = p[15];

    int c0 = (int)cntSelF[b]; c0 = c0 < SEL_CAP ? c0 : SEL_CAP;
    for (int i = t; i < c0; i += 256) seedF[i] = (int)selF[(size_t)b*SEL_CAP + i].y;
    int m = (int)cntScF[b]; m = m < CAND_CAP ? m : CAND_CAP;
    for (int i = t; i < m; i += 256) c[i] = scandF[(size_t)b*CAND_CAP + i];
    if (t == 0){ nF = c0; nB = 0; }
    __syncthreads();
    for (int i = t; i < m; i += 256){
        u32 ki = c[i].x, xi = c[i].y;
        int r = 0;
        for (int j = 0; j < m; j++){
            u32 kj = c[j].x, xj = c[j].y;
            r += (kj > ki) || (kj == ki && xj < xi);
        }
        if (r < needf){
            int q = atomicAdd(&nF, 1);
            if (q < SEL_CAP) seedF[q] = (int)xi;
        }
    }
    __syncthreads();
    int fN = nF; fN = fN < SEL_CAP ? fN : SEL_CAP;
    __syncthreads();

    int c0b = (int)cntSelB[b]; c0b = c0b < SEL_CAP ? c0b : SEL_CAP;
    for (int i = t; i < c0b; i += 256) seedB[i] = (int)selB[(size_t)b*SEL_CAP + i].y;
    int mb = (int)cntScB[b]; mb = mb < CAND_CAP ? mb : CAND_CAP;
    for (int i = t; i < mb; i += 256) c[i] = scandB[(size_t)b*CAND_CAP + i];
    if (t == 0) nB = c0b;
    __syncthreads();
    for (int i = t; i < mb; i += 256){
        u32 ki = c[i].x, xi = c[i].y;
        int r = 0;
        for (int j = 0; j < mb; j++){
            u32 kj = c[j].x, xj = c[j].y;
            r += (kj > ki) || (kj == ki && xj < xi);
        }
        if (r < needb){
            int q = atomicAdd(&nB, 1);
            if (q < SEL_CAP) seedB[q] = (int)xi;
        }
    }
    __syncthreads();
    int bN = nB; bN = bN < SEL_CAP ? bN : SEL_CAP;

    for (int i = t; i < fN; i += 256) gSeedF[b*SEL_CAP + i] = seedF[i];
    for (int i = t; i < bN; i += 256) gSeedB[b*SEL_CAP + i] = seedB[i];
    if (t == 0){ gnF[b] = fN; gnB[b] = bN; }
}

// K10: fill -255 and paint 3x3-dilated seeds with cross-set cancel
__global__ __launch_bounds__(256) void k_paint(
        const int* __restrict__ gSeedF, const int* __restrict__ gnF,
        const int* __restrict__ gSeedB, const int* __restrict__ gnB,
        int* __restrict__ out)
{
    __shared__ int sF[SEL_CAP], sB[SEL_CAP];
    int img = blockIdx.x >> 5, blk = blockIdx.x & 31, t = threadIdx.x;
    int fN = gnF[img]; fN = fN < SEL_CAP ? fN : SEL_CAP;
    int bN = gnB[img]; bN = bN < SEL_CAP ? bN : SEL_CAP;
    for (int i = t; i < fN; i += 256) sF[i] = gSeedF[img*SEL_CAP + i];
    for (int i = t; i < bN; i += 256) sB[i] = gSeedB[img*SEL_CAP + i];
    int4* o4 = (int4*)(out + (size_t)img*HWP + blk*8192);
    for (int i = t; i < 2048; i += 256) o4[i] = make_int4(-255,-255,-255,-255);
    __syncthreads();
    int row0 = blk * 16;
    int* outp = out + (size_t)img*HWP;
    for (int task = t; task < fN * 9; task += 256){
        int s = sF[task / 9];
        int o = task % 9;
        int y = (s >> 9) + (o / 3) - 1;
        int xx = (s & 511) + (o % 3) - 1;
        if (y < row0 || y >= row0 + 16 || xx < 0 || xx >= WW) continue;
        bool conf = false;
        for (int j = 0; j < bN; j++){
            int sb2 = sB[j];
            int dy = y - (sb2 >> 9); if (dy < 0) dy = -dy;
            int dx = xx - (sb2 & 511); if (dx < 0) dx = -dx;
            if (dy <= 1 && dx <= 1){ conf = true; break; }
        }
        if (!conf) outp[y * WW + xx] = 1;
    }
    for (int task = t; task < bN * 9; task += 256){
        int s = sB[task / 9];
        int o = task % 9;
        int y = (s >> 9) + (o / 3) - 1;
        int xx = (s & 511) + (o % 3) - 1;
        if (y < row0 || y >= row0 + 16 || xx < 0 || xx >= WW) continue;
        bool conf = false;
        for (int j = 0; j < fN; j++){
            int sf2 = sF[j];
            int dy = y - (sf2 >> 9); if (dy < 0) dy = -dy;
            int dx = xx - (sf2 & 511); if (dx < 0) dx = -dx;
            if (dy <= 1 && dx <= 1){ conf = true; break; }
        }
        if (!conf) outp[y * WW + xx] = 0;
    }
}

extern "C" void kernel_launch(void* const* d_in, const int* in_sizes, int n_in,
                              void* d_out, int out_size, void* d_ws, size_t ws_size,
                              hipStream_t stream)
{
    (void)in_sizes; (void)n_in; (void)out_size; (void)ws_size;
    const float* x   = (const float*)d_in[0];
    const float* thr = (const float*)d_in[1];
    const float* ufg = (const float*)d_in[2];
    const float* ubg = (const float*)d_in[3];
    int* out = (int*)d_out;
    char* ws = (char*)d_ws;

    size_t off = 0;
    auto carve = [&](size_t bytes) -> char* {
        char* ptr = ws + off;
        off = (off + bytes + 255) & ~(size_t)255;
        return ptr;
    };
    u32* ghist_bg = (u32*)carve((size_t)BB*NBV*4);
    u32* ghist_fg = (u32*)carve((size_t)BB*NBV*4);
    u32* shf      = (u32*)carve((size_t)BB*NBS*4);
    u32* shb      = (u32*)carve((size_t)BB*NBS*4);
    u32* cnts     = (u32*)carve((size_t)6*BB*4);
    u32* roiSum   = (u32*)carve((size_t)BB*4);
    u32* maxb     = (u32*)carve((size_t)BB*4);
    size_t zero_bytes = off;
    u32* minb     = (u32*)carve((size_t)BB*4);
    size_t minb_off = (size_t)((char*)minb - ws);
    u32* roiH     = (u32*)carve((size_t)BB*WPI*4);
    u32* roiE     = (u32*)carve((size_t)BB*WPI*4);
    int* prm      = (int*)carve((size_t)BB*PN*4);
    uint2* candF  = (uint2*)carve((size_t)BB*CAND_CAP*8);
    uint2* candB  = (uint2*)carve((size_t)BB*CAND_CAP*8);
    uint2* scandF = (uint2*)carve((size_t)BB*CAND_CAP*8);
    uint2* scandB = (uint2*)carve((size_t)BB*CAND_CAP*8);
    uint2* selF   = (uint2*)carve((size_t)BB*SEL_CAP*8);
    uint2* selB   = (uint2*)carve((size_t)BB*SEL_CAP*8);
    int* gSeedF   = (int*)carve((size_t)BB*SEL_CAP*4);
    int* gSeedB   = (int*)carve((size_t)BB*SEL_CAP*4);
    int* gnF      = (int*)carve((size_t)BB*4);
    int* gnB      = (int*)carve((size_t)BB*4);
    u32* cntF = cnts, *cntB = cnts + BB, *cntSelF = cnts + 2*BB,
       *cntScF = cnts + 3*BB, *cntSelB = cnts + 4*BB, *cntScB = cnts + 5*BB;

    hipMemsetAsync(ws, 0, zero_bytes, stream);
    hipMemsetAsync(ws + minb_off, 0xFF, (size_t)BB*4, stream);

    k_prep    <<<2048, 256, 0, stream>>>(x, thr, roiH, ghist_bg, minb, maxb);
    k_vfg     <<<2048, 256, 0, stream>>>(x, roiH, roiE, roiSum, ghist_fg);
    k_bound1  <<<64,   256, 0, stream>>>(ghist_fg, ghist_bg, minb, maxb, roiSum, prm);
    k_collect1<<<2048, 256, 0, stream>>>(x, roiE, prm, candF, cntF, candB, cntB);
    k_resolve1<<<64,   256, 0, stream>>>(candF, cntF, candB, cntB, prm);
    k_shist   <<<2048, 256, 0, stream>>>(x, roiE, ufg, ubg, prm, shf, shb);
    k_bound2  <<<64,   256, 0, stream>>>(shf, shb, prm);
    k_collect2<<<2048, 256, 0, stream>>>(x, roiE, ufg, ubg, prm,
                                         selF, cntSelF, scandF, cntScF,
                                         selB, cntSelB, scandB, cntScB);
    k_seeds   <<<64,   256, 0, stream>>>(selF, cntSelF, scandF, cntScF,
                                         selB, cntSelB, scandB, cntScB, prm,
                                         gSeedF, gnF, gSeedB, gnB);
    k_paint   <<<2048, 256, 0, stream>>>(gSeedF, gnF, gSeedB, gnB, out);
}

// Round 5
// 451.150 us; speedup vs baseline: 1.1459x; 1.1459x over previous
//
#include <hip/hip_runtime.h>

typedef unsigned int u32;

#define BB 64
#define HH 512
#define WW 512
#define HWP 262144            // 512*512
#define WPI 8192              // words per image (512*16)
#define NBV 1024              // value histogram bins
#define NBS 512               // score histogram bins
#define EPSF 1e-8f
#define NBGK 78643            // int(0.3 * 512*512)
#define CAND_CAP 4096
#define SEL_CAP 128
#define PN 12
#define CP 16                 // counter padding stride (u32s) to avoid line bounce

// prm fields per image: 0 nfg, 1 deg, 2 Bf, 3 rf, 4 Bb, 5 rb, 6 ubf, 7 ibf, 8 ubb, 9 ibb

__device__ __forceinline__ int vbucket(float vb){
    int b = (int)(vb * (float)NBV);
    b = b < 0 ? 0 : b;
    return b > (NBV-1) ? (NBV-1) : b;
}
__device__ __forceinline__ int sbucket(float s){
    float a = (s + 24.0f) * ((float)NBS / 44.0f);
    a = fmaxf(a, 0.0f);
    int b = (int)a;
    return b > (NBS-1) ? (NBS-1) : b;
}
__device__ __forceinline__ u32 flipf(float s){
    u32 u = __float_as_uint(s);
    u32 m = (u & 0x80000000u) ? 0xFFFFFFFFu : 0x80000000u;
    return u ^ m;
}

// Parallel k-th order-statistic from a histogram (256 threads).
// DESC: scan from top bin down. res[0]=bucket, res[1]=rank within bucket (1-based).
template<int NB, int BPT, bool DESC>
__device__ __forceinline__ void hist_kth(const u32* __restrict__ hh, int target,
        int* partial, int* res, int t){
    int s = 0;
    #pragma unroll
    for (int i = 0; i < BPT; i++){
        int b = DESC ? (NB-1 - (t*BPT+i)) : (t*BPT+i);
        s += (int)hh[b];
    }
    partial[t] = s;
    __syncthreads();
    for (int off = 1; off < 256; off <<= 1){
        int v = partial[t];
        int u = (t >= off) ? partial[t-off] : 0;
        __syncthreads();
        partial[t] = v + u;
        __syncthreads();
    }
    int incl = partial[t];
    int above = incl - s;
    if (above < target && target <= incl){
        int cum = above;
        #pragma unroll
        for (int i = 0; i < BPT; i++){
            int b = DESC ? (NB-1 - (t*BPT+i)) : (t*BPT+i);
            int h = (int)hh[b];
            if (cum + h >= target){ res[0] = b; res[1] = target - cum; break; }
            cum += h;
        }
    }
    __syncthreads();
}

// K1: roi bits (LDS) -> h-erode -> roiH; bg value hist; min/max.
__global__ __launch_bounds__(256) void k_prep(const float* __restrict__ x,
        const float* __restrict__ thr, u32* __restrict__ roiH,
        u32* __restrict__ ghist_bg, u32* __restrict__ minb, u32* __restrict__ maxb)
{
    __shared__ u32 hist[NBV];
    __shared__ u32 A[256];
    int t = threadIdx.x;
    for (int i = t; i < NBV; i += 256) hist[i] = 0u;
    A[t] = 0u;
    __syncthreads();
    int img = blockIdx.x >> 5, blk = blockIdx.x & 31;
    const float4* c4 = (const float4*)x + (size_t)img * (HWP/4) + (size_t)blk * 2048;
    float th = thr[img];
    th = (th == 0.0f) ? 1.0f : ((th == 255.0f) ? 254.0f : th);
    float4 v[8];
    #pragma unroll
    for (int k = 0; k < 8; k++) v[k] = c4[k*256 + t];
    u32 mn = 0xFFFFFFFFu, mx = 0u;
    #pragma unroll
    for (int k = 0; k < 8; k++){
        float vv[4] = {v[k].x, v[k].y, v[k].z, v[k].w};
        u32 nib = 0u;
        #pragma unroll
        for (int c = 0; c < 4; c++){
            float vl = vv[c];
            u32 ub = __float_as_uint(vl);
            mn = mn < ub ? mn : ub;
            mx = mx > ub ? mx : ub;
            if (floorf(vl * 255.0f) > th) nib |= (1u << c);
            atomicAdd(&hist[vbucket(vl + EPSF)], 1u);
        }
        if (nib) atomicOr(&A[k*32 + (t>>3)], nib << ((t&7)*4));
    }
    for (int o = 32; o >= 1; o >>= 1){
        u32 m2 = __shfl_down(mn, o); mn = mn < m2 ? mn : m2;
        u32 m3 = __shfl_down(mx, o); mx = mx > m3 ? mx : m3;
    }
    if ((t & 63) == 0){ atomicMin(&minb[img], mn); atomicMax(&maxb[img], mx); }
    __syncthreads();
    {
        int wr = t & 15;
        u32 cur = A[t];
        u32 left  = (wr > 0)  ? A[t-1] : 0xFFFFFFFFu;
        u32 right = (wr < 15) ? A[t+1] : 0xFFFFFFFFu;
        u32 res = cur;
        #pragma unroll
        for (int d = 1; d <= 5; d++){
            res &= (cur >> d) | (right << (32 - d));
            res &= (cur << d) | (left  >> (32 - d));
        }
        roiH[(size_t)img*WPI + blk*256 + t] = res;
    }
    for (int i = t; i < NBV; i += 256){
        u32 h = hist[i];
        if (h) atomicAdd(&ghist_bg[(size_t)img*NBV + i], h);
    }
}

// K2: v-erode roiH -> roiE + roiSum, fused fg value histogram.
__global__ __launch_bounds__(256) void k_vfg(const float* __restrict__ x,
        const u32* __restrict__ roiH, u32* __restrict__ roiE,
        u32* __restrict__ roiSum, u32* __restrict__ ghist_fg)
{
    __shared__ u32 hist[NBV];
    __shared__ u32 W[256];
    int t = threadIdx.x;
    for (int i = t; i < NBV; i += 256) hist[i] = 0u;
    int img = blockIdx.x >> 5, blk = blockIdx.x & 31;
    const u32* rp = roiH + (size_t)img * WPI;
    int iw = blk*256 + t;
    int r = iw >> 4;
    u32 res = 0xFFFFFFFFu;
    #pragma unroll
    for (int d = -5; d <= 5; d++){
        int rr = r + d;
        if (rr >= 0 && rr < HH) res &= rp[iw + d*16];
    }
    W[t] = res;
    roiE[(size_t)img*WPI + iw] = res;
    u32 cnt = __popc(res);
    for (int o = 32; o >= 1; o >>= 1) cnt += __shfl_down(cnt, o);
    if ((t & 63) == 0) atomicAdd(&roiSum[img], cnt);
    __syncthreads();
    const float4* c4 = (const float4*)x + (size_t)img * (HWP/4) + (size_t)blk * 2048;
    u32 nb[8];
    float4 vv[8];
    #pragma unroll
    for (int k = 0; k < 8; k++){
        nb[k] = (W[k*32 + (t>>3)] >> ((t&7)*4)) & 0xFu;
        if (nb[k]) vv[k] = c4[k*256 + t];
    }
    #pragma unroll
    for (int k = 0; k < 8; k++){
        if (nb[k]){
            float vl[4] = {vv[k].x, vv[k].y, vv[k].z, vv[k].w};
            #pragma unroll
            for (int c = 0; c < 4; c++){
                if ((nb[k] >> c) & 1u) atomicAdd(&hist[vbucket(vl[c] + EPSF)], 1u);
            }
        }
    }
    __syncthreads();
    for (int i = t; i < NBV; i += 256){
        u32 h = hist[i];
        if (h) atomicAdd(&ghist_fg[(size_t)img*NBV + i], h);
    }
}

// K3: head = bound1 (parallel hist scan); body = collect boundary candidates.
__global__ __launch_bounds__(256) void k_collect1(const float* __restrict__ x, const u32* __restrict__ roiE,
        const u32* __restrict__ ghf, const u32* __restrict__ ghb,
        const u32* __restrict__ minb, const u32* __restrict__ maxb, const u32* __restrict__ roiSum,
        int* __restrict__ prm,
        uint2* __restrict__ candF, u32* __restrict__ cntF,
        uint2* __restrict__ candB, u32* __restrict__ cntB)
{
    __shared__ int partial[256];
    __shared__ int res[2];
    __shared__ u32 words[256];
    int img = blockIdx.x >> 5, blk = blockIdx.x & 31, t = threadIdx.x;
    int deg = (minb[img] == maxb[img]) ? 1 : 0;
    int nfg = (int)floorf(0.3f * (float)(int)roiSum[img]);
    int Bf = -1, rf = 0, Bb = -1, rb = 0;
    if (!deg && nfg > 0){
        hist_kth<NBV,4,true>(ghf + (size_t)img*NBV, nfg, partial, res, t);
        Bf = res[0]; rf = res[1];
    }
    if (!deg){
        hist_kth<NBV,4,false>(ghb + (size_t)img*NBV, NBGK, partial, res, t);
        Bb = res[0]; rb = res[1];
    }
    if (blk == 0 && t == 0){
        int* p = prm + img*PN;
        p[0] = nfg; p[1] = deg; p[2] = Bf; p[3] = rf; p[4] = Bb; p[5] = rb;
    }
    words[t] = roiE[(size_t)img*WPI + blk*256 + t];
    __syncthreads();
    const float4* c4 = (const float4*)x + (size_t)img * (HWP/4) + (size_t)blk * 2048;
    float4 v[8];
    #pragma unroll
    for (int k = 0; k < 8; k++) v[k] = c4[k*256 + t];
    #pragma unroll
    for (int k = 0; k < 8; k++){
        float vv[4] = {v[k].x, v[k].y, v[k].z, v[k].w};
        u32 nib = (words[k*32 + (t>>3)] >> ((t&7)*4)) & 0xFu;
        int pix0 = blk*8192 + k*1024 + t*4;
        #pragma unroll
        for (int c = 0; c < 4; c++){
            float vb = vv[c] + EPSF;
            int bkt = vbucket(vb);
            int pix = pix0 + c;
            if (bkt == Bb){
                u32 q = atomicAdd(&cntB[img*CP], 1u);
                if (q < CAND_CAP) candB[(size_t)img*CAND_CAP + q] = make_uint2(__float_as_uint(vb), (u32)pix);
            }
            if (bkt == Bf && ((nib >> c) & 1u)){
                u32 q = atomicAdd(&cntF[img*CP], 1u);
                if (q < CAND_CAP) candF[(size_t)img*CAND_CAP + q] = make_uint2(__float_as_uint(vb), (u32)pix);
            }
        }
    }
}

// K4: resolve exact (bits, idx) threshold within boundary bucket
__global__ __launch_bounds__(256) void k_resolve1(const uint2* __restrict__ candF, const u32* __restrict__ cntF,
        const uint2* __restrict__ candB, const u32* __restrict__ cntB, int* __restrict__ prm)
{
    int b = blockIdx.x, t = threadIdx.x;
    __shared__ uint2 c[CAND_CAP];
    int rf = prm[b*PN + 3];
    if (rf > 0){
        int m = (int)cntF[b*CP]; m = m < CAND_CAP ? m : CAND_CAP;
        for (int i = t; i < m; i += 256) c[i] = candF[(size_t)b*CAND_CAP + i];
        __syncthreads();
        for (int i = t; i < m; i += 256){
            u32 ki = c[i].x, xi = c[i].y;
            int r = 0;
            for (int j = 0; j < m; j++){
                u32 kj = c[j].x, xj = c[j].y;
                r += (kj > ki) || (kj == ki && xj < xi);
            }
            if (r == rf - 1){ prm[b*PN + 6] = (int)ki; prm[b*PN + 7] = (int)xi; }
        }
    } else if (t == 0){
        prm[b*PN + 6] = (int)0xFFFFFFFFu; prm[b*PN + 7] = -1;
    }
    __syncthreads();
    int rb = prm[b*PN + 5];
    if (rb > 0){
        int m = (int)cntB[b*CP]; m = m < CAND_CAP ? m : CAND_CAP;
        for (int i = t; i < m; i += 256) c[i] = candB[(size_t)b*CAND_CAP + i];
        __syncthreads();
        for (int i = t; i < m; i += 256){
            u32 ki = c[i].x, xi = c[i].y;
            int r = 0;
            for (int j = 0; j < m; j++){
                u32 kj = c[j].x, xj = c[j].y;
                r += (kj < ki) || (kj == ki && xj < xi);
            }
            if (r == rb - 1){ prm[b*PN + 8] = (int)ki; prm[b*PN + 9] = (int)xi; }
        }
    } else if (t == 0){
        prm[b*PN + 8] = 0; prm[b*PN + 9] = -1;
    }
}

// K5: score histograms for masked fg/bg pixels
__global__ __launch_bounds__(256) void k_shist(const float* __restrict__ x, const u32* __restrict__ roiE,
        const float* __restrict__ ufg, const float* __restrict__ ubg, const int* __restrict__ prm,
        u32* __restrict__ shfG, u32* __restrict__ shbG)
{
    __shared__ u32 hf[NBS];
    __shared__ u32 hb[NBS];
    __shared__ u32 words[256];
    int t = threadIdx.x;
    for (int i = t; i < NBS; i += 256){ hf[i] = 0u; hb[i] = 0u; }
    int img = blockIdx.x >> 5, blk = blockIdx.x & 31;
    words[t] = roiE[(size_t)img*WPI + blk*256 + t];
    __syncthreads();
    const int* p = prm + img*PN;
    u32 ubf = (u32)p[6]; int ibf = p[7];
    u32 ubb = (u32)p[8]; int ibb = p[9];
    size_t b4 = (size_t)img * (HWP/4) + (size_t)blk * 2048;
    const float4* c4 = (const float4*)x + b4;
    const float4* uf4 = (const float4*)ufg + b4;
    const float4* ub4 = (const float4*)ubg + b4;
    float4 v[8];
    #pragma unroll
    for (int k = 0; k < 8; k++) v[k] = c4[k*256 + t];
    u32 fmsk = 0u, bmsk = 0u;
    #pragma unroll
    for (int k = 0; k < 8; k++){
        float vv[4] = {v[k].x, v[k].y, v[k].z, v[k].w};
        u32 nib = (words[k*32 + (t>>3)] >> ((t&7)*4)) & 0xFu;
        int pix0 = blk*8192 + k*1024 + t*4;
        #pragma unroll
        for (int c = 0; c < 4; c++){
            float vb = vv[c] + EPSF;
            u32 bu = __float_as_uint(vb);
            int pix = pix0 + c;
            if (((nib >> c) & 1u) && (bu > ubf || (bu == ubf && pix <= ibf))) fmsk |= 1u << (k*4+c);
            if (bu < ubb || (bu == ubb && pix <= ibb)) bmsk |= 1u << (k*4+c);
        }
    }
    float4 uf[8];
    #pragma unroll
    for (int k = 0; k < 8; k++) if ((fmsk >> (k*4)) & 0xFu) uf[k] = uf4[k*256 + t];
    #pragma unroll
    for (int k = 0; k < 8; k++){
        if ((fmsk >> (k*4)) & 0xFu){
            float vv[4] = {v[k].x, v[k].y, v[k].z, v[k].w};
            float uu[4] = {uf[k].x, uf[k].y, uf[k].z, uf[k].w};
            #pragma unroll
            for (int c = 0; c < 4; c++){
                if ((fmsk >> (k*4+c)) & 1u){
                    float s = logf(vv[c] + EPSF) - logf(-logf(uu[c]));
                    atomicAdd(&hf[sbucket(s)], 1u);
                }
            }
        }
    }
    float4 ub[8];
    #pragma unroll
    for (int k = 0; k < 8; k++) if ((bmsk >> (k*4)) & 0xFu) ub[k] = ub4[k*256 + t];
    #pragma unroll
    for (int k = 0; k < 8; k++){
        if ((bmsk >> (k*4)) & 0xFu){
            float vv[4] = {v[k].x, v[k].y, v[k].z, v[k].w};
            float uu[4] = {ub[k].x, ub[k].y, ub[k].z, ub[k].w};
            #pragma unroll
            for (int c = 0; c < 4; c++){
                if ((bmsk >> (k*4+c)) & 1u){
                    float pb = fmaxf(1.0f - (vv[c] + EPSF), 0.0f) + EPSF;
                    float s = logf(pb) - logf(-logf(uu[c]));
                    atomicAdd(&hb[sbucket(s)], 1u);
                }
            }
        }
    }
    __syncthreads();
    for (int i = t; i < NBS; i += 256){
        u32 h = hf[i]; if (h) atomicAdd(&shfG[(size_t)img*NBS + i], h);
        h = hb[i];     if (h) atomicAdd(&shbG[(size_t)img*NBS + i], h);
    }
}

// K6: head = bound2 (parallel scan of score hists); body = collect winners/candidates.
__global__ __launch_bounds__(256) void k_collect2(const float* __restrict__ x, const u32* __restrict__ roiE,
        const float* __restrict__ ufg, const float* __restrict__ ubg, const int* __restrict__ prm,
        const u32* __restrict__ shfG, const u32* __restrict__ shbG,
        uint2* __restrict__ selF, u32* __restrict__ cntSelF, uint2* __restrict__ scandF, u32* __restrict__ cntScF,
        uint2* __restrict__ selB, u32* __restrict__ cntSelB, uint2* __restrict__ scandB, u32* __restrict__ cntScB)
{
    __shared__ int partial[256];
    __shared__ int res[2];
    __shared__ u32 words[256];
    int img = blockIdx.x >> 5, blk = blockIdx.x & 31, t = threadIdx.x;
    const int* p = prm + img*PN;
    int nfg = p[0], deg = p[1];
    int kf = (deg || nfg <= 0) ? 0 : (nfg < 100 ? nfg : 100);
    int kb = deg ? 0 : 100;
    int sbf = 0x7FFFFFFF, sbb = 0x7FFFFFFF;
    if (kf > 0){
        hist_kth<NBS,2,true>(shfG + (size_t)img*NBS, kf, partial, res, t);
        sbf = res[0];
    }
    if (kb > 0){
        hist_kth<NBS,2,true>(shbG + (size_t)img*NBS, kb, partial, res, t);
        sbb = res[0];
    }
    u32 ubf = (u32)p[6]; int ibf = p[7];
    u32 ubb = (u32)p[8]; int ibb = p[9];
    words[t] = roiE[(size_t)img*WPI + blk*256 + t];
    __syncthreads();
    size_t b4 = (size_t)img * (HWP/4) + (size_t)blk * 2048;
    const float4* c4 = (const float4*)x + b4;
    const float4* uf4 = (const float4*)ufg + b4;
    const float4* ub4 = (const float4*)ubg + b4;
    float4 v[8];
    #pragma unroll
    for (int k = 0; k < 8; k++) v[k] = c4[k*256 + t];
    u32 fmsk = 0u, bmsk = 0u;
    #pragma unroll
    for (int k = 0; k < 8; k++){
        float vv[4] = {v[k].x, v[k].y, v[k].z, v[k].w};
        u32 nib = (words[k*32 + (t>>3)] >> ((t&7)*4)) & 0xFu;
        int pix0 = blk*8192 + k*1024 + t*4;
        #pragma unroll
        for (int c = 0; c < 4; c++){
            float vb = vv[c] + EPSF;
            u32 bu = __float_as_uint(vb);
            int pix = pix0 + c;
            if (((nib >> c) & 1u) && (bu > ubf || (bu == ubf && pix <= ibf))) fmsk |= 1u << (k*4+c);
            if (bu < ubb || (bu == ubb && pix <= ibb)) bmsk |= 1u << (k*4+c);
        }
    }
    float4 uf[8];
    #pragma unroll
    for (int k = 0; k < 8; k++) if ((fmsk >> (k*4)) & 0xFu) uf[k] = uf4[k*256 + t];
    #pragma unroll
    for (int k = 0; k < 8; k++){
        if ((fmsk >> (k*4)) & 0xFu){
            float vv[4] = {v[k].x, v[k].y, v[k].z, v[k].w};
            float uu[4] = {uf[k].x, uf[k].y, uf[k].z, uf[k].w};
            int pix0 = blk*8192 + k*1024 + t*4;
            #pragma unroll
            for (int c = 0; c < 4; c++){
                if ((fmsk >> (k*4+c)) & 1u){
                    float s = logf(vv[c] + EPSF) - logf(-logf(uu[c]));
                    int sb = sbucket(s);
                    if (sb > sbf){
                        u32 q = atomicAdd(&cntSelF[img*CP], 1u);
                        if (q < SEL_CAP) selF[(size_t)img*SEL_CAP + q] = make_uint2(flipf(s), (u32)(pix0 + c));
                    } else if (sb == sbf){
                        u32 q = atomicAdd(&cntScF[img*CP], 1u);
                        if (q < CAND_CAP) scandF[(size_t)img*CAND_CAP + q] = make_uint2(flipf(s), (u32)(pix0 + c));
                    }
                }
            }
        }
    }
    float4 ub[8];
    #pragma unroll
    for (int k = 0; k < 8; k++) if ((bmsk >> (k*4)) & 0xFu) ub[k] = ub4[k*256 + t];
    #pragma unroll
    for (int k = 0; k < 8; k++){
        if ((bmsk >> (k*4)) & 0xFu){
            float vv[4] = {v[k].x, v[k].y, v[k].z, v[k].w};
            float uu[4] = {ub[k].x, ub[k].y, ub[k].z, ub[k].w};
            int pix0 = blk*8192 + k*1024 + t*4;
            #pragma unroll
            for (int c = 0; c < 4; c++){
                if ((bmsk >> (k*4+c)) & 1u){
                    float pb = fmaxf(1.0f - (vv[c] + EPSF), 0.0f) + EPSF;
                    float s = logf(pb) - logf(-logf(uu[c]));
                    int sb = sbucket(s);
                    if (sb > sbb){
                        u32 q = atomicAdd(&cntSelB[img*CP], 1u);
                        if (q < SEL_CAP) selB[(size_t)img*SEL_CAP + q] = make_uint2(flipf(s), (u32)(pix0 + c));
                    } else if (sb == sbb){
                        u32 q = atomicAdd(&cntScB[img*CP], 1u);
                        if (q < CAND_CAP) scandB[(size_t)img*CAND_CAP + q] = make_uint2(flipf(s), (u32)(pix0 + c));
                    }
                }
            }
        }
    }
}

// K7: head re-derives (sbf,needf,sbb,needb); finalize top-k seed lists.
__global__ __launch_bounds__(256) void k_seeds(
        const uint2* __restrict__ selF, const u32* __restrict__ cntSelF,
        const uint2* __restrict__ scandF, const u32* __restrict__ cntScF,
        const uint2* __restrict__ selB, const u32* __restrict__ cntSelB,
        const uint2* __restrict__ scandB, const u32* __restrict__ cntScB,
        const u32* __restrict__ shfG, const u32* __restrict__ shbG,
        const int* __restrict__ prm,
        int* __restrict__ gSeedF, int* __restrict__ gnF,
        int* __restrict__ gSeedB, int* __restrict__ gnB)
{
    int b = blockIdx.x, t = threadIdx.x;
    __shared__ uint2 c[CAND_CAP];
    __shared__ int partial[256];
    __shared__ int res[2];
    __shared__ int seedF[SEL_CAP];
    __shared__ int seedB[SEL_CAP];
    __shared__ int nF, nB;
    const int* p = prm + b*PN;
    int nfg = p[0], deg = p[1];
    int kf = (deg || nfg <= 0) ? 0 : (nfg < 100 ? nfg : 100);
    int kb = deg ? 0 : 100;
    int needf = 0, needb = 0;
    if (kf > 0){
        hist_kth<NBS,2,true>(shfG + (size_t)b*NBS, kf, partial, res, t);
        needf = res[1];
    }
    if (kb > 0){
        hist_kth<NBS,2,true>(shbG + (size_t)b*NBS, kb, partial, res, t);
        needb = res[1];
    }

    int c0 = (int)cntSelF[b*CP]; c0 = c0 < SEL_CAP ? c0 : SEL_CAP;
    for (int i = t; i < c0; i += 256) seedF[i] = (int)selF[(size_t)b*SEL_CAP + i].y;
    int m = (int)cntScF[b*CP]; m = m < CAND_CAP ? m : CAND_CAP;
    for (int i = t; i < m; i += 256) c[i] = scandF[(size_t)b*CAND_CAP + i];
    if (t == 0){ nF = c0; nB = 0; }
    __syncthreads();
    for (int i = t; i < m; i += 256){
        u32 ki = c[i].x, xi = c[i].y;
        int r = 0;
        for (int j = 0; j < m; j++){
            u32 kj = c[j].x, xj = c[j].y;
            r += (kj > ki) || (kj == ki && xj < xi);
        }
        if (r < needf){
            int q = atomicAdd(&nF, 1);
            if (q < SEL_CAP) seedF[q] = (int)xi;
        }
    }
    __syncthreads();
    int fN = nF; fN = fN < SEL_CAP ? fN : SEL_CAP;
    __syncthreads();

    int c0b = (int)cntSelB[b*CP]; c0b = c0b < SEL_CAP ? c0b : SEL_CAP;
    for (int i = t; i < c0b; i += 256) seedB[i] = (int)selB[(size_t)b*SEL_CAP + i].y;
    int mb = (int)cntScB[b*CP]; mb = mb < CAND_CAP ? mb : CAND_CAP;
    for (int i = t; i < mb; i += 256) c[i] = scandB[(size_t)b*CAND_CAP + i];
    if (t == 0) nB = c0b;
    __syncthreads();
    for (int i = t; i < mb; i += 256){
        u32 ki = c[i].x, xi = c[i].y;
        int r = 0;
        for (int j = 0; j < mb; j++){
            u32 kj = c[j].x, xj = c[j].y;
            r += (kj > ki) || (kj == ki && xj < xi);
        }
        if (r < needb){
            int q = atomicAdd(&nB, 1);
            if (q < SEL_CAP) seedB[q] = (int)xi;
        }
    }
    __syncthreads();
    int bN = nB; bN = bN < SEL_CAP ? bN : SEL_CAP;

    for (int i = t; i < fN; i += 256) gSeedF[b*SEL_CAP + i] = seedF[i];
    for (int i = t; i < bN; i += 256) gSeedB[b*SEL_CAP + i] = seedB[i];
    if (t == 0){ gnF[b] = fN; gnB[b] = bN; }
}

// K8: fill -255 and paint 3x3-dilated seeds with cross-set cancel
__global__ __launch_bounds__(256) void k_paint(
        const int* __restrict__ gSeedF, const int* __restrict__ gnF,
        const int* __restrict__ gSeedB, const int* __restrict__ gnB,
        int* __restrict__ out)
{
    __shared__ int sF[SEL_CAP], sB[SEL_CAP];
    int img = blockIdx.x >> 5, blk = blockIdx.x & 31, t = threadIdx.x;
    int fN = gnF[img]; fN = fN < SEL_CAP ? fN : SEL_CAP;
    int bN = gnB[img]; bN = bN < SEL_CAP ? bN : SEL_CAP;
    for (int i = t; i < fN; i += 256) sF[i] = gSeedF[img*SEL_CAP + i];
    for (int i = t; i < bN; i += 256) sB[i] = gSeedB[img*SEL_CAP + i];
    int4* o4 = (int4*)(out + (size_t)img*HWP + blk*8192);
    #pragma unroll
    for (int i = 0; i < 8; i++) o4[i*256 + t] = make_int4(-255,-255,-255,-255);
    __syncthreads();
    int row0 = blk * 16;
    int* outp = out + (size_t)img*HWP;
    for (int task = t; task < fN * 9; task += 256){
        int s = sF[task / 9];
        int o = task % 9;
        int y = (s >> 9) + (o / 3) - 1;
        int xx = (s & 511) + (o % 3) - 1;
        if (y < row0 || y >= row0 + 16 || xx < 0 || xx >= WW) continue;
        bool conf = false;
        for (int j = 0; j < bN; j++){
            int sb2 = sB[j];
            int dy = y - (sb2 >> 9); if (dy < 0) dy = -dy;
            int dx = xx - (sb2 & 511); if (dx < 0) dx = -dx;
            if (dy <= 1 && dx <= 1){ conf = true; break; }
        }
        if (!conf) outp[y * WW + xx] = 1;
    }
    for (int task = t; task < bN * 9; task += 256){
        int s = sB[task / 9];
        int o = task % 9;
        int y = (s >> 9) + (o / 3) - 1;
        int xx = (s & 511) + (o % 3) - 1;
        if (y < row0 || y >= row0 + 16 || xx < 0 || xx >= WW) continue;
        bool conf = false;
        for (int j = 0; j < fN; j++){
            int sf2 = sF[j];
            int dy = y - (sf2 >> 9); if (dy < 0) dy = -dy;
            int dx = xx - (sf2 & 511); if (dx < 0) dx = -dx;
            if (dy <= 1 && dx <= 1){ conf = true; break; }
        }
        if (!conf) outp[y * WW + xx] = 0;
    }
}

extern "C" void kernel_launch(void* const* d_in, const int* in_sizes, int n_in,
                              void* d_out, int out_size, void* d_ws, size_t ws_size,
                              hipStream_t stream)
{
    (void)in_sizes; (void)n_in; (void)out_size; (void)ws_size;
    const float* x   = (const float*)d_in[0];
    const float* thr = (const float*)d_in[1];
    const float* ufg = (const float*)d_in[2];
    const float* ubg = (const float*)d_in[3];
    int* out = (int*)d_out;
    char* ws = (char*)d_ws;

    size_t off = 0;
    auto carve = [&](size_t bytes) -> char* {
        char* ptr = ws + off;
        off = (off + bytes + 255) & ~(size_t)255;
        return ptr;
    };
    u32* ghist_bg = (u32*)carve((size_t)BB*NBV*4);
    u32* ghist_fg = (u32*)carve((size_t)BB*NBV*4);
    u32* shf      = (u32*)carve((size_t)BB*NBS*4);
    u32* shb      = (u32*)carve((size_t)BB*NBS*4);
    u32* cnts     = (u32*)carve((size_t)6*BB*CP*4);
    u32* roiSum   = (u32*)carve((size_t)BB*4);
    u32* maxb     = (u32*)carve((size_t)BB*4);
    size_t zero_bytes = off;
    u32* minb     = (u32*)carve((size_t)BB*4);
    size_t minb_off = (size_t)((char*)minb - ws);
    u32* roiH     = (u32*)carve((size_t)BB*WPI*4);
    u32* roiE     = (u32*)carve((size_t)BB*WPI*4);
    int* prm      = (int*)carve((size_t)BB*PN*4);
    uint2* candF  = (uint2*)carve((size_t)BB*CAND_CAP*8);
    uint2* candB  = (uint2*)carve((size_t)BB*CAND_CAP*8);
    uint2* scandF = (uint2*)carve((size_t)BB*CAND_CAP*8);
    uint2* scandB = (uint2*)carve((size_t)BB*CAND_CAP*8);
    uint2* selF   = (uint2*)carve((size_t)BB*SEL_CAP*8);
    uint2* selB   = (uint2*)carve((size_t)BB*SEL_CAP*8);
    int* gSeedF   = (int*)carve((size_t)BB*SEL_CAP*4);
    int* gSeedB   = (int*)carve((size_t)BB*SEL_CAP*4);
    int* gnF      = (int*)carve((size_t)BB*4);
    int* gnB      = (int*)carve((size_t)BB*4);
    u32* cntF = cnts, *cntB = cnts + BB*CP, *cntSelF = cnts + 2*BB*CP,
       *cntScF = cnts + 3*BB*CP, *cntSelB = cnts + 4*BB*CP, *cntScB = cnts + 5*BB*CP;

    hipMemsetAsync(ws, 0, zero_bytes, stream);
    hipMemsetAsync(ws + minb_off, 0xFF, (size_t)BB*4, stream);

    k_prep    <<<2048, 256, 0, stream>>>(x, thr, roiH, ghist_bg, minb, maxb);
    k_vfg     <<<2048, 256, 0, stream>>>(x, roiH, roiE, roiSum, ghist_fg);
    k_collect1<<<2048, 256, 0, stream>>>(x, roiE, ghist_fg, ghist_bg, minb, maxb, roiSum,
                                         prm, candF, cntF, candB, cntB);
    k_resolve1<<<64,   256, 0, stream>>>(candF, cntF, candB, cntB, prm);
    k_shist   <<<2048, 256, 0, stream>>>(x, roiE, ufg, ubg, prm, shf, shb);
    k_collect2<<<2048, 256, 0, stream>>>(x, roiE, ufg, ubg, prm, shf, shb,
                                         selF, cntSelF, scandF, cntScF,
                                         selB, cntSelB, scandB, cntScB);
    k_seeds   <<<64,   256, 0, stream>>>(selF, cntSelF, scandF, cntScF,
                                         selB, cntSelB, scandB, cntScB,
                                         shf, shb, prm, gSeedF, gnF, gSeedB, gnB);
    k_paint   <<<2048, 256, 0, stream>>>(gSeedF, gnF, gSeedB, gnB, out);
}

// Round 6
// 423.496 us; speedup vs baseline: 1.2207x; 1.0653x over previous
//
#include <hip/hip_runtime.h>

typedef unsigned int u32;

#define BB 64
#define HH 512
#define WW 512
#define HWP 262144            // 512*512
#define WPI 8192              // words per image (512*16)
#define NBV 1024              // value histogram bins
#define NBS 512               // score histogram bins
#define EPSF 1e-8f
#define NBGK 78643            // int(0.3 * 512*512)
#define CAND_CAP 4096
#define SEL_CAP 128
#define SBLK 144              // per-block top-k list capacity
#define POOL 5120             // merge pool capacity (32*SBLK + boundary)
#define PN 12
#define CP 16                 // counter padding stride (u32s)

// prm per image: 0 nfg, 1 deg, 2 Bf, 3 rf, 4 Bb, 5 rb

__device__ __forceinline__ int vbucket(float vb){
    int b = (int)(vb * (float)NBV);
    b = b < 0 ? 0 : b;
    return b > (NBV-1) ? (NBV-1) : b;
}
__device__ __forceinline__ int sbucket(float s){
    float a = (s + 24.0f) * ((float)NBS / 44.0f);
    a = fmaxf(a, 0.0f);
    int b = (int)a;
    return b > (NBS-1) ? (NBS-1) : b;
}
__device__ __forceinline__ u32 flipf(float s){
    u32 u = __float_as_uint(s);
    u32 m = (u & 0x80000000u) ? 0xFFFFFFFFu : 0x80000000u;
    return u ^ m;
}
__device__ __forceinline__ float unflipf(u32 f){
    u32 orig = (f & 0x80000000u) ? (f ^ 0x80000000u) : ~f;
    return __uint_as_float(orig);
}

// kth order statistic from a histogram. res[0]=bucket, res[1]=in-bucket rank (1-based).
template<int NB, int BPT, bool DESC>
__device__ __forceinline__ void hist_kth(const u32* hh, int target,
        int* partial, int* res, int t){
    int s = 0;
    #pragma unroll
    for (int i = 0; i < BPT; i++){
        int b = DESC ? (NB-1 - (t*BPT+i)) : (t*BPT+i);
        s += (int)hh[b];
    }
    partial[t] = s;
    __syncthreads();
    for (int off = 1; off < 256; off <<= 1){
        int v = partial[t];
        int u = (t >= off) ? partial[t-off] : 0;
        __syncthreads();
        partial[t] = v + u;
        __syncthreads();
    }
    int incl = partial[t];
    int above = incl - s;
    if (above < target && target <= incl){
        int cum = above;
        #pragma unroll
        for (int i = 0; i < BPT; i++){
            int b = DESC ? (NB-1 - (t*BPT+i)) : (t*BPT+i);
            int h = (int)hh[b];
            if (cum + h >= target){ res[0] = b; res[1] = target - cum; break; }
            cum += h;
        }
    }
    __syncthreads();
}

// top-K boundary bucket (desc). bbOut = bucket of the K-th (or NB if target==0),
// targOut = min(K, total).
template<int NB, int BPT>
__device__ __forceinline__ void topk_desc(const u32* hh, int K,
        int* partial, int* res, int t, int& bbOut, int& targOut){
    int s = 0;
    #pragma unroll
    for (int i = 0; i < BPT; i++) s += (int)hh[NB-1 - (t*BPT+i)];
    partial[t] = s;
    __syncthreads();
    for (int off = 1; off < 256; off <<= 1){
        int v = partial[t];
        int u = (t >= off) ? partial[t-off] : 0;
        __syncthreads();
        partial[t] = v + u;
        __syncthreads();
    }
    int total = partial[255];
    int target = K < total ? K : total;
    int incl = partial[t], above = incl - s;
    if (target > 0 && above < target && target <= incl){
        int cum = above;
        #pragma unroll
        for (int i = 0; i < BPT; i++){
            int b = NB-1 - (t*BPT+i);
            int h = (int)hh[b];
            if (cum + h >= target){ res[0] = b; break; }
            cum += h;
        }
    }
    __syncthreads();
    bbOut = (target > 0) ? res[0] : NB;
    targOut = target;
    __syncthreads();
}

// K1: fused roi-threshold + halo h/v-erode (26 rows in LDS) + bg/fg value hists + min/max.
__global__ __launch_bounds__(256) void k_hist(const float* __restrict__ x,
        const float* __restrict__ thr, u32* __restrict__ roiE, u32* __restrict__ roiSum,
        u32* __restrict__ ghist_bg, u32* __restrict__ ghist_fg,
        u32* __restrict__ minb, u32* __restrict__ maxb)
{
    __shared__ u32 hb2[NBV];
    __shared__ u32 hf2[NBV];
    __shared__ u32 rawA[416];   // 26 rows x 16 words
    __shared__ u32 eH[416];
    __shared__ u32 W[256];
    int t = threadIdx.x;
    int img = blockIdx.x >> 5, blk = blockIdx.x & 31;
    int r0 = blk * 16;
    for (int i = t; i < NBV; i += 256){ hb2[i] = 0u; hf2[i] = 0u; }
    for (int i = t; i < 416; i += 256){
        int gr = r0 - 5 + (i >> 4);
        rawA[i] = (gr < 0 || gr >= HH) ? 0xFFFFFFFFu : 0u;
    }
    __syncthreads();
    const float4* c4img = (const float4*)x + (size_t)img * (HWP/4);
    const float4* c4 = c4img + (size_t)blk * 2048;
    float th = thr[img];
    th = (th == 0.0f) ? 1.0f : ((th == 255.0f) ? 254.0f : th);
    float4 v[8];
    #pragma unroll
    for (int k = 0; k < 8; k++) v[k] = c4[k*256 + t];
    float4 hv[5];
    #pragma unroll
    for (int j = 0; j < 5; j++){
        int fi = j*256 + t;
        int hl = fi >> 7;
        int gr = (hl < 5) ? (r0 - 5 + hl) : (r0 + 16 + (hl - 5));
        if (gr >= 0 && gr < HH) hv[j] = c4img[gr*128 + (fi & 127)];
    }
    u32 mn = 0xFFFFFFFFu, mx = 0u;
    #pragma unroll
    for (int k = 0; k < 8; k++){
        float vv[4] = {v[k].x, v[k].y, v[k].z, v[k].w};
        u32 nib = 0u;
        #pragma unroll
        for (int c = 0; c < 4; c++){
            float vl = vv[c];
            u32 ub = __float_as_uint(vl);
            mn = mn < ub ? mn : ub;
            mx = mx > ub ? mx : ub;
            if (floorf(vl * 255.0f) > th) nib |= (1u << c);
            atomicAdd(&hb2[vbucket(vl + EPSF)], 1u);
        }
        if (nib) atomicOr(&rawA[(k*2 + (t>>7) + 5)*16 + ((t&127)>>3)], nib << ((t&7)*4));
    }
    #pragma unroll
    for (int j = 0; j < 5; j++){
        int fi = j*256 + t;
        int hl = fi >> 7;
        int gr = (hl < 5) ? (r0 - 5 + hl) : (r0 + 16 + (hl - 5));
        if (gr >= 0 && gr < HH){
            float vv[4] = {hv[j].x, hv[j].y, hv[j].z, hv[j].w};
            u32 nib = 0u;
            #pragma unroll
            for (int c = 0; c < 4; c++)
                if (floorf(vv[c] * 255.0f) > th) nib |= (1u << c);
            int hr = (hl < 5) ? hl : (16 + hl);
            if (nib) atomicOr(&rawA[hr*16 + ((fi&127)>>3)], nib << ((fi&7)*4));
        }
    }
    for (int o = 32; o >= 1; o >>= 1){
        u32 m2 = __shfl_down(mn, o); mn = mn < m2 ? mn : m2;
        u32 m3 = __shfl_down(mx, o); mx = mx > m3 ? mx : m3;
    }
    if ((t & 63) == 0){ atomicMin(&minb[img], mn); atomicMax(&maxb[img], mx); }
    __syncthreads();
    for (int i = t; i < 416; i += 256){
        int wr = i & 15;
        u32 cur = rawA[i];
        u32 left  = (wr > 0)  ? rawA[i-1] : 0xFFFFFFFFu;
        u32 right = (wr < 15) ? rawA[i+1] : 0xFFFFFFFFu;
        u32 res = cur;
        #pragma unroll
        for (int d = 1; d <= 5; d++){
            res &= (cur >> d) | (right << (32 - d));
            res &= (cur << d) | (left  >> (32 - d));
        }
        eH[i] = res;
    }
    __syncthreads();
    {
        int wr = t & 15;
        int hr = (t >> 4) + 5;
        u32 res = 0xFFFFFFFFu;
        #pragma unroll
        for (int d = -5; d <= 5; d++) res &= eH[(hr + d)*16 + wr];
        W[t] = res;
        roiE[(size_t)img*WPI + blk*256 + t] = res;
        u32 cnt = __popc(res);
        for (int o = 32; o >= 1; o >>= 1) cnt += __shfl_down(cnt, o);
        if ((t & 63) == 0) atomicAdd(&roiSum[img], cnt);
    }
    __syncthreads();
    #pragma unroll
    for (int k = 0; k < 8; k++){
        u32 nib = (W[k*32 + (t>>3)] >> ((t&7)*4)) & 0xFu;
        if (nib){
            float vv[4] = {v[k].x, v[k].y, v[k].z, v[k].w};
            #pragma unroll
            for (int c = 0; c < 4; c++)
                if ((nib >> c) & 1u) atomicAdd(&hf2[vbucket(vv[c] + EPSF)], 1u);
        }
    }
    __syncthreads();
    for (int i = t; i < NBV; i += 256){
        u32 h = hb2[i]; if (h) atomicAdd(&ghist_bg[(size_t)img*NBV + i], h);
        h = hf2[i];     if (h) atomicAdd(&ghist_fg[(size_t)img*NBV + i], h);
    }
}

// K2: bound heads + boundary-candidate collect + score certain-mask pixels +
// per-block local top-100 lists (F and B).
__global__ __launch_bounds__(256) void k_select(const float* __restrict__ x,
        const u32* __restrict__ roiE, const float* __restrict__ ufg, const float* __restrict__ ubg,
        const u32* __restrict__ ghf, const u32* __restrict__ ghb,
        const u32* __restrict__ minb, const u32* __restrict__ maxb, const u32* __restrict__ roiSum,
        int* __restrict__ prm,
        uint2* __restrict__ candF, u32* __restrict__ cntF,
        uint2* __restrict__ candB, u32* __restrict__ cntB,
        uint2* __restrict__ blkF, int* __restrict__ blkFn,
        uint2* __restrict__ blkB, int* __restrict__ blkBn)
{
    __shared__ int partial[256];
    __shared__ int res[2];
    __shared__ u32 sh[NBS];
    __shared__ u32 words[256];
    __shared__ int sN;
    int img = blockIdx.x >> 5, blk = blockIdx.x & 31, t = threadIdx.x;
    int bid = blockIdx.x;
    int deg = (minb[img] == maxb[img]) ? 1 : 0;
    int nfg = (int)floorf(0.3f * (float)(int)roiSum[img]);
    bool doF = (!deg && nfg > 0), doB = !deg;
    int Bf = -1, rf = 0, Bb = -1, rb = 0;
    if (doF){
        hist_kth<NBV,4,true>(ghf + (size_t)img*NBV, nfg, partial, res, t);
        Bf = res[0]; rf = res[1];
        __syncthreads();
    }
    if (doB){
        hist_kth<NBV,4,false>(ghb + (size_t)img*NBV, NBGK, partial, res, t);
        Bb = res[0]; rb = res[1];
        __syncthreads();
    }
    if (blk == 0 && t == 0){
        int* p = prm + img*PN;
        p[0] = nfg; p[1] = deg; p[2] = Bf; p[3] = rf; p[4] = Bb; p[5] = rb;
    }
    words[t] = roiE[(size_t)img*WPI + blk*256 + t];
    size_t b4 = (size_t)img * (HWP/4) + (size_t)blk * 2048;
    const float4* c4 = (const float4*)x + b4;
    const float4* uf4 = (const float4*)ufg + b4;
    const float4* ub4 = (const float4*)ubg + b4;
    float4 v[8];
    #pragma unroll
    for (int k = 0; k < 8; k++) v[k] = c4[k*256 + t];
    __syncthreads();
    u32 certF = 0u, certB = 0u;
    #pragma unroll
    for (int k = 0; k < 8; k++){
        float vv[4] = {v[k].x, v[k].y, v[k].z, v[k].w};
        u32 nib = (words[k*32 + (t>>3)] >> ((t&7)*4)) & 0xFu;
        int pix0 = blk*8192 + k*1024 + t*4;
        #pragma unroll
        for (int c = 0; c < 4; c++){
            float vb = vv[c] + EPSF;
            int bkt = vbucket(vb);
            int bit = k*4 + c;
            if (doF && ((nib >> c) & 1u)){
                if (bkt > Bf) certF |= (1u << bit);
                else if (bkt == Bf){
                    u32 q = atomicAdd(&cntF[img*CP], 1u);
                    if (q < CAND_CAP) candF[(size_t)img*CAND_CAP + q] = make_uint2(__float_as_uint(vb), (u32)(pix0 + c));
                }
            }
            if (doB){
                if (bkt < Bb) certB |= (1u << bit);
                else if (bkt == Bb){
                    u32 q = atomicAdd(&cntB[img*CP], 1u);
                    if (q < CAND_CAP) candB[(size_t)img*CAND_CAP + q] = make_uint2(__float_as_uint(vb), (u32)(pix0 + c));
                }
            }
        }
    }
    // ---- F side: local top-100 ----
    for (int i = t; i < NBS; i += 256) sh[i] = 0u;
    __syncthreads();
    if (certF){
        #pragma unroll
        for (int k = 0; k < 8; k++){
            u32 nb4 = (certF >> (k*4)) & 0xFu;
            if (nb4){
                float4 u4 = uf4[k*256 + t];
                float uu[4] = {u4.x, u4.y, u4.z, u4.w};
                float vv[4] = {v[k].x, v[k].y, v[k].z, v[k].w};
                #pragma unroll
                for (int c = 0; c < 4; c++){
                    if ((nb4 >> c) & 1u){
                        float s = logf(vv[c] + EPSF) - logf(-logf(uu[c]));
                        atomicAdd(&sh[sbucket(s)], 1u);
                    }
                }
            }
        }
    }
    __syncthreads();
    int bbF, targF;
    topk_desc<NBS,2>(sh, 100, partial, res, t, bbF, targF);
    if (t == 0) sN = 0;
    __syncthreads();
    if (targF > 0 && certF){
        #pragma unroll
        for (int k = 0; k < 8; k++){
            u32 nb4 = (certF >> (k*4)) & 0xFu;
            if (nb4){
                float4 u4 = uf4[k*256 + t];
                float uu[4] = {u4.x, u4.y, u4.z, u4.w};
                float vv[4] = {v[k].x, v[k].y, v[k].z, v[k].w};
                int pix0 = blk*8192 + k*1024 + t*4;
                #pragma unroll
                for (int c = 0; c < 4; c++){
                    if ((nb4 >> c) & 1u){
                        float s = logf(vv[c] + EPSF) - logf(-logf(uu[c]));
                        if (sbucket(s) >= bbF){
                            int q = atomicAdd(&sN, 1);
                            if (q < SBLK) blkF[(size_t)bid*SBLK + q] = make_uint2(flipf(s), (u32)(pix0 + c));
                        }
                    }
                }
            }
        }
    }
    __syncthreads();
    if (t == 0) blkFn[bid] = sN < SBLK ? sN : SBLK;
    __syncthreads();
    // ---- B side: local top-100 ----
    for (int i = t; i < NBS; i += 256) sh[i] = 0u;
    __syncthreads();
    if (certB){
        #pragma unroll
        for (int k = 0; k < 8; k++){
            u32 nb4 = (certB >> (k*4)) & 0xFu;
            if (nb4){
                float4 u4 = ub4[k*256 + t];
                float uu[4] = {u4.x, u4.y, u4.z, u4.w};
                float vv[4] = {v[k].x, v[k].y, v[k].z, v[k].w};
                #pragma unroll
                for (int c = 0; c < 4; c++){
                    if ((nb4 >> c) & 1u){
                        float pb = fmaxf(1.0f - (vv[c] + EPSF), 0.0f) + EPSF;
                        float s = logf(pb) - logf(-logf(uu[c]));
                        atomicAdd(&sh[sbucket(s)], 1u);
                    }
                }
            }
        }
    }
    __syncthreads();
    int bbB, targB;
    topk_desc<NBS,2>(sh, 100, partial, res, t, bbB, targB);
    if (t == 0) sN = 0;
    __syncthreads();
    if (targB > 0 && certB){
        #pragma unroll
        for (int k = 0; k < 8; k++){
            u32 nb4 = (certB >> (k*4)) & 0xFu;
            if (nb4){
                float4 u4 = ub4[k*256 + t];
                float uu[4] = {u4.x, u4.y, u4.z, u4.w};
                float vv[4] = {v[k].x, v[k].y, v[k].z, v[k].w};
                int pix0 = blk*8192 + k*1024 + t*4;
                #pragma unroll
                for (int c = 0; c < 4; c++){
                    if ((nb4 >> c) & 1u){
                        float pb = fmaxf(1.0f - (vv[c] + EPSF), 0.0f) + EPSF;
                        float s = logf(pb) - logf(-logf(uu[c]));
                        if (sbucket(s) >= bbB){
                            int q = atomicAdd(&sN, 1);
                            if (q < SBLK) blkB[(size_t)bid*SBLK + q] = make_uint2(flipf(s), (u32)(pix0 + c));
                        }
                    }
                }
            }
        }
    }
    __syncthreads();
    if (t == 0) blkBn[bid] = sN < SBLK ? sN : SBLK;
}

// K3: per (img,side): exact boundary resolve + score in-mask boundary px,
// merge 32 block lists + boundary -> exact top-k -> seeds.
__global__ __launch_bounds__(256) void k_merge(
        const uint2* __restrict__ candF, const u32* __restrict__ cntF,
        const uint2* __restrict__ candB, const u32* __restrict__ cntB,
        const uint2* __restrict__ blkF, const int* __restrict__ blkFn,
        const uint2* __restrict__ blkB, const int* __restrict__ blkBn,
        const int* __restrict__ prm, const float* __restrict__ ufg, const float* __restrict__ ubg,
        int* __restrict__ gSeedF, int* __restrict__ gnF,
        int* __restrict__ gSeedB, int* __restrict__ gnB)
{
    __shared__ uint2 pool[POOL];
    __shared__ uint2 lc[1024];
    __shared__ u32 sh[NBS];
    __shared__ int partial[256];
    __shared__ int res[2];
    __shared__ int pN, lcN, sN;
    int img = blockIdx.x >> 1, side = blockIdx.x & 1, t = threadIdx.x;
    const int* p = prm + img*PN;
    int nfg = p[0], deg = p[1];
    int K = (side == 0) ? ((deg || nfg <= 0) ? 0 : (nfg < 100 ? nfg : 100))
                        : (deg ? 0 : 100);
    int* gn = (side == 0) ? gnF : gnB;
    int* gs = (side == 0) ? gSeedF : gSeedB;
    if (K == 0){ if (t == 0) gn[img] = 0; return; }
    int r_in = (side == 0) ? p[3] : p[5];
    const uint2* cand = (side == 0) ? candF : candB;
    const u32* cnt = (side == 0) ? cntF : cntB;
    const uint2* bl = (side == 0) ? blkF : blkB;
    const int* bln = (side == 0) ? blkFn : blkBn;
    const float* uu = (side == 0) ? ufg : ubg;
    if (t == 0){ lcN = 0; pN = 0; }
    int m = (int)cnt[img*CP]; m = m < CAND_CAP ? m : CAND_CAP;
    for (int i = t; i < m; i += 256) pool[i] = cand[(size_t)img*CAND_CAP + i];
    __syncthreads();
    for (int i = t; i < m; i += 256){
        u32 ki = pool[i].x, xi = pool[i].y;
        int r = 0;
        for (int j = 0; j < m; j++){
            u32 kj = pool[j].x, xj = pool[j].y;
            if (side == 0) r += (kj > ki) || (kj == ki && xj < xi);
            else           r += (kj < ki) || (kj == ki && xj < xi);
        }
        if (r < r_in){
            float vb = __uint_as_float(ki);
            float uv = uu[(size_t)img*HWP + xi];
            float s;
            if (side == 0) s = logf(vb) - logf(-logf(uv));
            else { float pb = fmaxf(1.0f - vb, 0.0f) + EPSF; s = logf(pb) - logf(-logf(uv)); }
            int q = atomicAdd(&lcN, 1);
            if (q < 1024) lc[q] = make_uint2(flipf(s), xi);
        }
    }
    __syncthreads();
    for (int idx = t; idx < 32*SBLK; idx += 256){
        int b2 = idx / SBLK, i2 = idx % SBLK;
        int n = bln[img*32 + b2];
        if (i2 < n){
            int q = atomicAdd(&pN, 1);
            if (q < POOL) pool[q] = bl[(size_t)(img*32 + b2)*SBLK + i2];
        }
    }
    __syncthreads();
    int ln = lcN < 1024 ? lcN : 1024;
    for (int i = t; i < ln; i += 256){
        int q = atomicAdd(&pN, 1);
        if (q < POOL) pool[q] = lc[i];
    }
    __syncthreads();
    int P = pN < POOL ? pN : POOL;
    for (int i = t; i < NBS; i += 256) sh[i] = 0u;
    __syncthreads();
    for (int i = t; i < P; i += 256)
        atomicAdd(&sh[sbucket(unflipf(pool[i].x))], 1u);
    __syncthreads();
    int bb, targ;
    topk_desc<NBS,2>(sh, K, partial, res, t, bb, targ);
    if (t == 0) sN = 0;
    __syncthreads();
    for (int i = t; i < P; i += 256){
        if (sbucket(unflipf(pool[i].x)) >= bb){
            int q = atomicAdd(&sN, 1);
            if (q < 1024) lc[q] = pool[i];
        }
    }
    __syncthreads();
    int mm = sN < 1024 ? sN : 1024;
    for (int i = t; i < mm; i += 256){
        u32 ki = lc[i].x, xi = lc[i].y;
        int r = 0;
        for (int j = 0; j < mm; j++){
            u32 kj = lc[j].x, xj = lc[j].y;
            r += (kj > ki) || (kj == ki && xj < xi);
        }
        if (r < targ) gs[img*SEL_CAP + r] = (int)xi;
    }
    if (t == 0) gn[img] = targ;
}

// K4: fill -255 and paint 3x3-dilated seeds with cross-set cancel.
__global__ __launch_bounds__(256) void k_paint(
        const int* __restrict__ gSeedF, const int* __restrict__ gnF,
        const int* __restrict__ gSeedB, const int* __restrict__ gnB,
        int* __restrict__ out)
{
    __shared__ int sF[SEL_CAP], sB[SEL_CAP];
    int img = blockIdx.x >> 5, blk = blockIdx.x & 31, t = threadIdx.x;
    int fN = gnF[img]; fN = fN < SEL_CAP ? fN : SEL_CAP;
    int bN = gnB[img]; bN = bN < SEL_CAP ? bN : SEL_CAP;
    for (int i = t; i < fN; i += 256) sF[i] = gSeedF[img*SEL_CAP + i];
    for (int i = t; i < bN; i += 256) sB[i] = gSeedB[img*SEL_CAP + i];
    int4* o4 = (int4*)(out + (size_t)img*HWP + blk*8192);
    #pragma unroll
    for (int i = 0; i < 8; i++) o4[i*256 + t] = make_int4(-255,-255,-255,-255);
    __syncthreads();
    int row0 = blk * 16;
    int* outp = out + (size_t)img*HWP;
    for (int task = t; task < fN * 9; task += 256){
        int s = sF[task / 9];
        int o = task % 9;
        int y = (s >> 9) + (o / 3) - 1;
        int xx = (s & 511) + (o % 3) - 1;
        if (y < row0 || y >= row0 + 16 || xx < 0 || xx >= WW) continue;
        bool conf = false;
        for (int j = 0; j < bN; j++){
            int sb2 = sB[j];
            int dy = y - (sb2 >> 9); if (dy < 0) dy = -dy;
            int dx = xx - (sb2 & 511); if (dx < 0) dx = -dx;
            if (dy <= 1 && dx <= 1){ conf = true; break; }
        }
        if (!conf) outp[y * WW + xx] = 1;
    }
    for (int task = t; task < bN * 9; task += 256){
        int s = sB[task / 9];
        int o = task % 9;
        int y = (s >> 9) + (o / 3) - 1;
        int xx = (s & 511) + (o % 3) - 1;
        if (y < row0 || y >= row0 + 16 || xx < 0 || xx >= WW) continue;
        bool conf = false;
        for (int j = 0; j < fN; j++){
            int sf2 = sF[j];
            int dy = y - (sf2 >> 9); if (dy < 0) dy = -dy;
            int dx = xx - (sf2 & 511); if (dx < 0) dx = -dx;
            if (dy <= 1 && dx <= 1){ conf = true; break; }
        }
        if (!conf) outp[y * WW + xx] = 0;
    }
}

extern "C" void kernel_launch(void* const* d_in, const int* in_sizes, int n_in,
                              void* d_out, int out_size, void* d_ws, size_t ws_size,
                              hipStream_t stream)
{
    (void)in_sizes; (void)n_in; (void)out_size; (void)ws_size;
    const float* x   = (const float*)d_in[0];
    const float* thr = (const float*)d_in[1];
    const float* ufg = (const float*)d_in[2];
    const float* ubg = (const float*)d_in[3];
    int* out = (int*)d_out;
    char* ws = (char*)d_ws;

    size_t off = 0;
    auto carve = [&](size_t bytes) -> char* {
        char* ptr = ws + off;
        off = (off + bytes + 255) & ~(size_t)255;
        return ptr;
    };
    u32* ghist_bg = (u32*)carve((size_t)BB*NBV*4);
    u32* ghist_fg = (u32*)carve((size_t)BB*NBV*4);
    u32* cnts     = (u32*)carve((size_t)2*BB*CP*4);
    u32* roiSum   = (u32*)carve((size_t)BB*4);
    u32* maxb     = (u32*)carve((size_t)BB*4);
    size_t zero_bytes = off;
    u32* minb     = (u32*)carve((size_t)BB*4);
    size_t minb_off = (size_t)((char*)minb - ws);
    u32* roiE     = (u32*)carve((size_t)BB*WPI*4);
    int* prm      = (int*)carve((size_t)BB*PN*4);
    uint2* candF  = (uint2*)carve((size_t)BB*CAND_CAP*8);
    uint2* candB  = (uint2*)carve((size_t)BB*CAND_CAP*8);
    uint2* blkF   = (uint2*)carve((size_t)2048*SBLK*8);
    uint2* blkB   = (uint2*)carve((size_t)2048*SBLK*8);
    int* blkFn    = (int*)carve((size_t)2048*4);
    int* blkBn    = (int*)carve((size_t)2048*4);
    int* gSeedF   = (int*)carve((size_t)BB*SEL_CAP*4);
    int* gSeedB   = (int*)carve((size_t)BB*SEL_CAP*4);
    int* gnF      = (int*)carve((size_t)BB*4);
    int* gnB      = (int*)carve((size_t)BB*4);
    u32* cntF = cnts, *cntB = cnts + BB*CP;

    hipMemsetAsync(ws, 0, zero_bytes, stream);
    hipMemsetAsync(ws + minb_off, 0xFF, (size_t)BB*4, stream);

    k_hist  <<<2048, 256, 0, stream>>>(x, thr, roiE, roiSum, ghist_bg, ghist_fg, minb, maxb);
    k_select<<<2048, 256, 0, stream>>>(x, roiE, ufg, ubg, ghist_fg, ghist_bg,
                                       minb, maxb, roiSum, prm,
                                       candF, cntF, candB, cntB,
                                       blkF, blkFn, blkB, blkBn);
    k_merge <<<128,  256, 0, stream>>>(candF, cntF, candB, cntB,
                                       blkF, blkFn, blkB, blkBn,
                                       prm, ufg, ubg, gSeedF, gnF, gSeedB, gnB);
    k_paint <<<2048, 256, 0, stream>>>(gSeedF, gnF, gSeedB, gnB, out);
}